// Round 7
// baseline (469.078 us; speedup 1.0000x reference)
//
#include <hip/hip_runtime.h>
#include <cstdint>

// Transformer Post-LN block, MI355X gfx950.
// B=4, L=2048, FEA=512, H=8, DK=64, FFN=2048. f32 I/O, bf16 MFMA, f32 accum.
// Round 7: attention computes S^T/O^T (packed b64 P-writes, aligned b128
// reads, l via ones-MFMA, packed 8B Z stores); QKV pre-converts activations
// to bf16 and stages via global_load_lds (register-staging fallback if the
// workspace is small). GEMM/LN/transpose structure unchanged from r6.

typedef __bf16 bf16;
typedef __bf16 bf16x4 __attribute__((ext_vector_type(4)));
typedef __bf16 bf16x8 __attribute__((ext_vector_type(8)));
typedef float floatx4 __attribute__((ext_vector_type(4)));

__device__ __forceinline__ floatx4 mfma_bf16(bf16x8 a, bf16x8 b, floatx4 c) {
  return __builtin_amdgcn_mfma_f32_16x16x32_bf16(a, b, c, 0, 0, 0);
}

// async global->LDS, 16B/lane; LDS dest = wave-uniform base + lane*16.
__device__ __forceinline__ void load_lds_16(const void* g, void* l) {
  auto gp = reinterpret_cast<const void __attribute__((address_space(1)))*>(
      reinterpret_cast<uintptr_t>(g));
  auto lp = reinterpret_cast<void __attribute__((address_space(3)))*>(
      (unsigned int)reinterpret_cast<uintptr_t>(l));
  __builtin_amdgcn_global_load_lds(gp, lp, 16, 0, 0);
}

// tanh-form GELU (max |err| ~1e-3, well under the 0.0988 threshold)
__device__ __forceinline__ float gelu_f(float x) {
  float t = 0.7978845608f * (x + 0.044715f * x * x * x);
  float e = __builtin_amdgcn_exp2f(t * 2.885390082f);  // e^(2t)
  float th = 1.0f - 2.0f * __builtin_amdgcn_rcpf(e + 1.0f);
  return 0.5f * x * (1.0f + th);
}

// k-plane LDS geometry: plane = rows*16B, +16B pad between planes.
#define PLANE128 2064  // 128 rows * 16B + 16B pad
#define PLANE64 1040   // 64 rows * 16B + 16B pad
#define PSTR 72        // P^T tile row stride (bf16): [q][kk], 16B-aligned rows

// ---- fused weight transpose (4x 512x512) + f32->bf16 ----------------------
__global__ void __launch_bounds__(256) transpose4_k(const float* __restrict__ w0,
                                                    const float* __restrict__ w1,
                                                    const float* __restrict__ w2,
                                                    const float* __restrict__ w3,
                                                    bf16* __restrict__ o0,
                                                    bf16* __restrict__ o1,
                                                    bf16* __restrict__ o2,
                                                    bf16* __restrict__ o3) {
  const float* in = (blockIdx.z == 0) ? w0 : (blockIdx.z == 1) ? w1
                    : (blockIdx.z == 2) ? w2 : w3;
  bf16* out = (blockIdx.z == 0) ? o0 : (blockIdx.z == 1) ? o1
              : (blockIdx.z == 2) ? o2 : o3;
  __shared__ float tile[32][33];
  int m0 = blockIdx.x * 32, k0 = blockIdx.y * 32;
  int tx = threadIdx.x, ty = threadIdx.y;  // (32, 8)
  for (int i = ty; i < 32; i += 8)
    tile[i][tx] = in[(size_t)(k0 + i) * 512 + m0 + tx];
  __syncthreads();
  for (int i = ty; i < 32; i += 8)
    out[(size_t)(m0 + i) * 512 + k0 + tx] = (bf16)tile[tx][i];
}

__global__ void __launch_bounds__(256) transpose_k(const float* __restrict__ in,
                                                   bf16* __restrict__ out,
                                                   int K, int M) {
  __shared__ float tile[32][33];
  int m0 = blockIdx.x * 32, k0 = blockIdx.y * 32;
  int tx = threadIdx.x, ty = threadIdx.y;
  for (int i = ty; i < 32; i += 8)
    tile[i][tx] = in[(size_t)(k0 + i) * M + m0 + tx];
  __syncthreads();
  for (int i = ty; i < 32; i += 8)
    out[(size_t)(m0 + i) * K + k0 + tx] = (bf16)tile[tx][i];
}

// ---- f32 -> bf16 bulk convert of {qx,kx,vx} into one buffer ---------------
__global__ void __launch_bounds__(256) cvt3_k(const float* __restrict__ a,
                                              const float* __restrict__ b,
                                              const float* __restrict__ c,
                                              bf16* __restrict__ out) {
  int seg = blockIdx.x >> 12;  // 4096 blocks per tensor
  const float* in = (seg == 0) ? a : (seg == 1) ? b : c;
  int i = ((blockIdx.x & 4095) * 256 + threadIdx.x) * 4;
  float4 v = *(const float4*)(in + i);
  bf16x4 o;
  o[0] = (bf16)v.x; o[1] = (bf16)v.y; o[2] = (bf16)v.z; o[3] = (bf16)v.w;
  *(bf16x4*)(out + (size_t)seg * 4194304 + i) = o;
}

// ---- maskPAD int32 -> bitmask (bit=1 keep) --------------------------------
__global__ void __launch_bounds__(256) maskbits_k(const int* __restrict__ m,
                                                  unsigned long long* __restrict__ out) {
  int w = blockIdx.x * 4 + (threadIdx.x >> 6);
  int lane = threadIdx.x & 63;
  int v = m[(size_t)w * 64 + lane];
  unsigned long long b = __ballot(v != 0);
  if (lane == 0) out[w] = b;
}

// ---- epilogue helper ------------------------------------------------------
template <int EPI>
__device__ __forceinline__ void epi_store(void* Cout, int n, int m, int M,
                                          float val) {
  if constexpr (EPI == 1) {  // bf16 scatter [B,H,L,DK]
    int bb = n >> 11, l = n & 2047, hh = m >> 6, d = m & 63;
    ((bf16*)Cout)[((size_t)((bb * 8 + hh) * 2048 + l)) * 64 + d] = (bf16)val;
  } else if constexpr (EPI == 2) {  // bf16 scatter [B,H,DK,L]
    int bb = n >> 11, l = n & 2047, hh = m >> 6, d = m & 63;
    ((bf16*)Cout)[((size_t)((bb * 8 + hh) * 64 + d)) * 2048 + l] = (bf16)val;
  } else if constexpr (EPI == 3) {  // GELU -> bf16
    ((bf16*)Cout)[(size_t)n * M + m] = (bf16)gelu_f(val);
  } else if constexpr (EPI == 4) {  // f32
    ((float*)Cout)[(size_t)n * M + m] = val;
  } else {  // f32 accumulate
    ((float*)Cout)[(size_t)n * M + m] += val;
  }
}

// ---- GEMM: C[N][M] = A[N][K] @ Bt[M][K]^T + bias, BK=64 -------------------
// WIDE: 128x128 tile, wave = 64x64 quadrant, acc 4x4.
// TALL: 128x64 tile, wave = 32 rows x 64 cols, acc 2x4. grid.x = M/64.
template <int EPI, bool TALL>
__global__ void __launch_bounds__(256) gemm_bt(const bf16* __restrict__ A,
                                               const bf16* __restrict__ Bt,
                                               const float* __restrict__ bias,
                                               void* __restrict__ Cout,
                                               int M, int K, int lda, int ldb) {
  __shared__ __attribute__((aligned(16))) char As[8 * PLANE128];
  __shared__ __attribute__((aligned(16))) char Bs[TALL ? 8 * PLANE64 : 8 * PLANE128];
  int tid = threadIdx.x, wave = tid >> 6, lane = tid & 63;
  int lrow = lane & 15, quad = lane >> 4;
  int n0 = blockIdx.y * 128;
  int m0 = blockIdx.x * (TALL ? 64 : 128);
  int wr = wave >> 1, wc = wave & 1;  // WIDE quadrant
  floatx4 zero4 = {0.f, 0.f, 0.f, 0.f};
  constexpr int NI = TALL ? 2 : 4;
  floatx4 acc[NI][4];
#pragma unroll
  for (int i = 0; i < NI; ++i)
#pragma unroll
    for (int j = 0; j < 4; ++j) acc[i][j] = zero4;
  for (int k0 = 0; k0 < K; k0 += 64) {
    __syncthreads();  // prior iter's frag reads done
#pragma unroll
    for (int h = 0; h < 2; ++h) {
      int p = wave + 4 * h;  // wave covers planes {wave, wave+4}
#pragma unroll
      for (int j = 0; j < 2; ++j) {
        int row = j * 64 + lane;
        load_lds_16(A + (size_t)(n0 + row) * lda + k0 + p * 8,
                    As + p * PLANE128 + j * 1024 + lane * 16);
      }
      if constexpr (TALL) {
        load_lds_16(Bt + (size_t)(m0 + lane) * ldb + k0 + p * 8,
                    Bs + p * PLANE64 + lane * 16);
      } else {
#pragma unroll
        for (int j = 0; j < 2; ++j) {
          int row = j * 64 + lane;
          load_lds_16(Bt + (size_t)(m0 + row) * ldb + k0 + p * 8,
                      Bs + p * PLANE128 + j * 1024 + lane * 16);
        }
      }
    }
    __syncthreads();  // vmcnt drained -> staging visible
#pragma unroll
    for (int h = 0; h < 2; ++h) {
      int pb = h * 4 + quad;
      bf16x8 af[NI], bfr[4];
#pragma unroll
      for (int i = 0; i < NI; ++i) {
        int row = (TALL ? wave * 32 : wr * 64) + i * 16 + lrow;
        af[i] = *(const bf16x8*)(As + pb * PLANE128 + row * 16);
      }
#pragma unroll
      for (int j = 0; j < 4; ++j) {
        if constexpr (TALL)
          bfr[j] = *(const bf16x8*)(Bs + pb * PLANE64 + (j * 16 + lrow) * 16);
        else
          bfr[j] = *(const bf16x8*)(Bs + pb * PLANE128 +
                                    (wc * 64 + j * 16 + lrow) * 16);
      }
#pragma unroll
      for (int i = 0; i < NI; ++i)
#pragma unroll
        for (int j = 0; j < 4; ++j)
          acc[i][j] = mfma_bf16(af[i], bfr[j], acc[i][j]);
    }
  }
  float bv[4];
#pragma unroll
  for (int j = 0; j < 4; ++j) {
    int m = m0 + (TALL ? 0 : wc * 64) + j * 16 + lrow;
    bv[j] = (EPI == 5) ? 0.f : bias[m];
  }
#pragma unroll
  for (int i = 0; i < NI; ++i)
#pragma unroll
    for (int j = 0; j < 4; ++j)
#pragma unroll
      for (int r = 0; r < 4; ++r) {
        int n = n0 + (TALL ? wave * 32 : wr * 64) + i * 16 + quad * 4 + r;
        int m = m0 + (TALL ? 0 : wc * 64) + j * 16 + lrow;
        epi_store<EPI>(Cout, n, m, M, acc[i][j][r] + bv[j]);
      }
}

// ---- fast QKV: pure async staging, A = pre-converted bf16 -----------------
// grid (4, 192): seg = y>>6 selects weight/bias/out/epilogue. BK=64.
__global__ void __launch_bounds__(256) qkv2_k(const bf16* __restrict__ xall,
                                              const bf16* __restrict__ wqT,
                                              const bf16* __restrict__ wkT,
                                              const bf16* __restrict__ wvT,
                                              const float* __restrict__ bq,
                                              const float* __restrict__ bk,
                                              const float* __restrict__ bv_,
                                              bf16* __restrict__ qh,
                                              bf16* __restrict__ kh,
                                              bf16* __restrict__ vt) {
  __shared__ __attribute__((aligned(16))) char As[8 * PLANE128];
  __shared__ __attribute__((aligned(16))) char Bs[8 * PLANE128];
  int tid = threadIdx.x, wave = tid >> 6, lane = tid & 63;
  int lrow = lane & 15, quad = lane >> 4;
  int seg = blockIdx.y >> 6;
  int n0 = (blockIdx.y & 63) * 128, m0 = blockIdx.x * 128;
  const bf16* A = xall + (size_t)seg * 4194304;
  const bf16* Bt = (seg == 0) ? wqT : (seg == 1) ? wkT : wvT;
  const float* bias = (seg == 0) ? bq : (seg == 1) ? bk : bv_;
  bf16* out = (seg == 0) ? qh : (seg == 1) ? kh : vt;
  int wr = wave >> 1, wc = wave & 1;
  floatx4 zero4 = {0.f, 0.f, 0.f, 0.f};
  floatx4 acc[4][4];
#pragma unroll
  for (int i = 0; i < 4; ++i)
#pragma unroll
    for (int j = 0; j < 4; ++j) acc[i][j] = zero4;
  for (int k0 = 0; k0 < 512; k0 += 64) {
    __syncthreads();
#pragma unroll
    for (int h = 0; h < 2; ++h) {
      int p = wave + 4 * h;
#pragma unroll
      for (int j = 0; j < 2; ++j) {
        int row = j * 64 + lane;
        load_lds_16(A + (size_t)(n0 + row) * 512 + k0 + p * 8,
                    As + p * PLANE128 + j * 1024 + lane * 16);
        load_lds_16(Bt + (size_t)(m0 + row) * 512 + k0 + p * 8,
                    Bs + p * PLANE128 + j * 1024 + lane * 16);
      }
    }
    __syncthreads();
#pragma unroll
    for (int h = 0; h < 2; ++h) {
      int pb = h * 4 + quad;
      bf16x8 af[4], bfr[4];
#pragma unroll
      for (int t = 0; t < 4; ++t) {
        af[t] = *(const bf16x8*)(As + pb * PLANE128 + (wr * 64 + t * 16 + lrow) * 16);
        bfr[t] = *(const bf16x8*)(Bs + pb * PLANE128 + (wc * 64 + t * 16 + lrow) * 16);
      }
#pragma unroll
      for (int i = 0; i < 4; ++i)
#pragma unroll
        for (int j = 0; j < 4; ++j) acc[i][j] = mfma_bf16(af[i], bfr[j], acc[i][j]);
    }
  }
  float bvv[4];
#pragma unroll
  for (int j = 0; j < 4; ++j) bvv[j] = bias[m0 + wc * 64 + j * 16 + lrow];
#pragma unroll
  for (int i = 0; i < 4; ++i)
#pragma unroll
    for (int j = 0; j < 4; ++j)
#pragma unroll
      for (int r = 0; r < 4; ++r) {
        int n = n0 + wr * 64 + i * 16 + quad * 4 + r;
        int m = m0 + wc * 64 + j * 16 + lrow;
        float val = acc[i][j][r] + bvv[j];
        int bb = n >> 11, l = n & 2047, hh = m >> 6, d = m & 63;
        if (seg == 2)
          out[((size_t)((bb * 8 + hh) * 64 + d)) * 2048 + l] = (bf16)val;
        else
          out[((size_t)((bb * 8 + hh) * 2048 + l)) * 64 + d] = (bf16)val;
      }
}

// ---- slow QKV fallback (r6): f32 A via register staging -------------------
__global__ void __launch_bounds__(256) qkv_k(const float* __restrict__ qx,
                                             const float* __restrict__ kx,
                                             const float* __restrict__ vx,
                                             const bf16* __restrict__ wqT,
                                             const bf16* __restrict__ wkT,
                                             const bf16* __restrict__ wvT,
                                             const float* __restrict__ bq,
                                             const float* __restrict__ bk,
                                             const float* __restrict__ bv_,
                                             bf16* __restrict__ qh,
                                             bf16* __restrict__ kh,
                                             bf16* __restrict__ vt) {
  __shared__ __attribute__((aligned(16))) char As[8 * PLANE128];
  __shared__ __attribute__((aligned(16))) char Bs[8 * PLANE128];
  int tid = threadIdx.x, wave = tid >> 6, lane = tid & 63;
  int lrow = lane & 15, quad = lane >> 4;
  int seg = blockIdx.y >> 6;
  int n0 = (blockIdx.y & 63) * 128, m0 = blockIdx.x * 128;
  const float* Af = (seg == 0) ? qx : (seg == 1) ? kx : vx;
  const bf16* Bt = (seg == 0) ? wqT : (seg == 1) ? wkT : wvT;
  const float* bias = (seg == 0) ? bq : (seg == 1) ? bk : bv_;
  bf16* out = (seg == 0) ? qh : (seg == 1) ? kh : vt;
  int wr = wave >> 1, wc = wave & 1;
  floatx4 zero4 = {0.f, 0.f, 0.f, 0.f};
  floatx4 acc[4][4];
#pragma unroll
  for (int i = 0; i < 4; ++i)
#pragma unroll
    for (int j = 0; j < 4; ++j) acc[i][j] = zero4;
  int arow = tid >> 2, ap = tid & 3;
  for (int k0 = 0; k0 < 512; k0 += 64) {
    bf16x8 a[4];
#pragma unroll
    for (int u = 0; u < 4; ++u) {
      int row = arow + (u & 1) * 64, p = ap + (u >> 1) * 4;
      const float* src = Af + (size_t)(n0 + row) * 512 + k0 + p * 8;
      float4 x0 = *(const float4*)src;
      float4 x1 = *(const float4*)(src + 4);
      a[u][0] = (bf16)x0.x; a[u][1] = (bf16)x0.y; a[u][2] = (bf16)x0.z;
      a[u][3] = (bf16)x0.w; a[u][4] = (bf16)x1.x; a[u][5] = (bf16)x1.y;
      a[u][6] = (bf16)x1.z; a[u][7] = (bf16)x1.w;
    }
    __syncthreads();
#pragma unroll
    for (int u = 0; u < 4; ++u) {
      int row = arow + (u & 1) * 64, p = ap + (u >> 1) * 4;
      *(bf16x8*)(As + p * PLANE128 + row * 16) = a[u];
    }
#pragma unroll
    for (int h = 0; h < 2; ++h) {
      int p = wave + 4 * h;
#pragma unroll
      for (int j = 0; j < 2; ++j) {
        int row = j * 64 + lane;
        load_lds_16(Bt + (size_t)(m0 + row) * 512 + k0 + p * 8,
                    Bs + p * PLANE128 + j * 1024 + lane * 16);
      }
    }
    __syncthreads();
#pragma unroll
    for (int h = 0; h < 2; ++h) {
      int pb = h * 4 + quad;
      bf16x8 af[4], bfr[4];
#pragma unroll
      for (int t = 0; t < 4; ++t) {
        af[t] = *(const bf16x8*)(As + pb * PLANE128 + (wr * 64 + t * 16 + lrow) * 16);
        bfr[t] = *(const bf16x8*)(Bs + pb * PLANE128 + (wc * 64 + t * 16 + lrow) * 16);
      }
#pragma unroll
      for (int i = 0; i < 4; ++i)
#pragma unroll
        for (int j = 0; j < 4; ++j) acc[i][j] = mfma_bf16(af[i], bfr[j], acc[i][j]);
    }
  }
  float bvv[4];
#pragma unroll
  for (int j = 0; j < 4; ++j) bvv[j] = bias[m0 + wc * 64 + j * 16 + lrow];
#pragma unroll
  for (int i = 0; i < 4; ++i)
#pragma unroll
    for (int j = 0; j < 4; ++j)
#pragma unroll
      for (int r = 0; r < 4; ++r) {
        int n = n0 + wr * 64 + i * 16 + quad * 4 + r;
        int m = m0 + wc * 64 + j * 16 + lrow;
        float val = acc[i][j][r] + bvv[j];
        int bb = n >> 11, l = n & 2047, hh = m >> 6, d = m & 63;
        if (seg == 2)
          out[((size_t)((bb * 8 + hh) * 64 + d)) * 2048 + l] = (bf16)val;
        else
          out[((size_t)((bb * 8 + hh) * 2048 + l)) * 64 + d] = (bf16)val;
      }
}

// ---- flash attention, S^T/O^T formulation ---------------------------------
// S^T = K·Q^T (A=K-frag, B=Q-frag): C/D lane (quad,lrow) reg r holds
// S^T[kk=nt*16+quad*4+r][q=lrow] -> 4 consecutive kk per lane -> packed
// b64 write into P^T[q][kk]; A/B-frag readback is aligned b128.
// O^T = V^T·P^T (A=V-frag, B=P-frag); l = mfma(ones, P) (per-lane scalar).
__global__ void __launch_bounds__(256) attn_k(const bf16* __restrict__ Qh,
                                              const bf16* __restrict__ Kh,
                                              const bf16* __restrict__ Vt,
                                              const unsigned long long* __restrict__ MB,
                                              bf16* __restrict__ Z) {
  __shared__ __attribute__((aligned(16))) char Ks[8 * PLANE64];
  __shared__ __attribute__((aligned(16))) char Vs[8 * PLANE64];
  __shared__ __attribute__((aligned(16))) bf16 Pt[4][16 * PSTR];  // [q][kk]
  int qt = blockIdx.x, h = blockIdx.y, b = blockIdx.z;
  int tid = threadIdx.x, wave = tid >> 6, lane = tid & 63;
  int lrow = lane & 15, quad = lane >> 4;
  int q0 = qt * 64;
  size_t headbase = (size_t)(b * 8 + h) * 2048 * 64;

  // Q as B-frag: lane n=lrow -> row q0+wave*16+lrow, k=quad*8+j
  const bf16* Qp = Qh + headbase + (size_t)(q0 + wave * 16 + lrow) * 64 + quad * 8;
  bf16x8 qf0 = *(const bf16x8*)Qp;
  bf16x8 qf1 = *(const bf16x8*)(Qp + 32);

  floatx4 zero4 = {0.f, 0.f, 0.f, 0.f};
  floatx4 o_acc[4], acc_l = zero4;  // o_acc[dt] = O^T[d-block dt][q]
#pragma unroll
  for (int dt = 0; dt < 4; ++dt) o_acc[dt] = zero4;
  bf16x8 ones;
#pragma unroll
  for (int j = 0; j < 8; ++j) ones[j] = (bf16)1.0f;

  const bf16* Vg = Vt + headbase;
  // per-lane mask row: q depends only on lrow
  const unsigned long long* MBrow =
      MB + ((size_t)b * 2048 + q0 + wave * 16 + lrow) * 32;
  bf16* Pw = Pt[wave];
  const float C = 0.1803368801f;  // 0.125 * log2(e)

  for (int kt = 0; kt < 32; ++kt) {
    int kk0 = kt * 64;
    const bf16* Kg = Kh + headbase + (size_t)kk0 * 64;
    __syncthreads();  // prior iter's Ks/Vs reads done
#pragma unroll
    for (int j = 0; j < 2; ++j) {
      int p = wave * 2 + j;
      load_lds_16(Kg + (size_t)lane * 64 + p * 8, Ks + p * PLANE64 + lane * 16);
      load_lds_16(Vg + (size_t)lane * 2048 + kk0 + p * 8,
                  Vs + p * PLANE64 + lane * 16);
    }
    unsigned long long mw = MBrow[kt];
    unsigned sx = (unsigned)(mw >> (quad * 4));        // nt 0 (bit r), nt 1 (bit 16+r)
    unsigned sy = (unsigned)(mw >> (32 + quad * 4));   // nt 2, nt 3
    __syncthreads();  // staging visible

#pragma unroll
    for (int nt = 0; nt < 4; ++nt) {
      int R = nt * 16 + lrow;  // K row (kk-local)
      bf16x8 k0f = *(const bf16x8*)(Ks + quad * PLANE64 + R * 16);
      bf16x8 k1f = *(const bf16x8*)(Ks + (quad + 4) * PLANE64 + R * 16);
      floatx4 aa = zero4;
      aa = mfma_bf16(k0f, qf0, aa);  // S^T[kk][q]
      aa = mfma_bf16(k1f, qf1, aa);
      unsigned sel = (nt < 2 ? sx : sy) >> ((nt & 1) * 16);
      bf16x4 pv;
#pragma unroll
      for (int r = 0; r < 4; ++r) {
        float e = __builtin_amdgcn_exp2f(aa[r] * C);
        pv[r] = (bf16)(((sel >> r) & 1u) ? e : 0.f);
      }
      // packed 8B write: P^T[q=lrow][kk = nt*16 + quad*4 .. +4]
      *(bf16x4*)(Pw + lrow * PSTR + nt * 16 + quad * 4) = pv;
    }
    // wave-private round trip (lgkmcnt-ordered, no barrier)
    bf16x8 pf0 = *(const bf16x8*)(Pw + lrow * PSTR + quad * 8);        // kk 0..31
    bf16x8 pf1 = *(const bf16x8*)(Pw + lrow * PSTR + 32 + quad * 8);   // kk 32..63
    acc_l = mfma_bf16(ones, pf0, acc_l);  // D[*][q] = l[q]
    acc_l = mfma_bf16(ones, pf1, acc_l);
#pragma unroll
    for (int dt = 0; dt < 4; ++dt) {
      int R = dt * 16 + lrow;  // V^T row (d)
      bf16x8 v0 = *(const bf16x8*)(Vs + quad * PLANE64 + R * 16);
      bf16x8 v1 = *(const bf16x8*)(Vs + (quad + 4) * PLANE64 + R * 16);
      o_acc[dt] = mfma_bf16(v0, pf0, o_acc[dt]);  // O^T[d][q]
      o_acc[dt] = mfma_bf16(v1, pf1, o_acc[dt]);
    }
  }
  // epilogue: per lane q = q0+wave*16+lrow; regs r = d = dt*16+quad*4+r
  float lr = __builtin_amdgcn_rcpf(acc_l[0]);
  size_t zrow = ((size_t)(b * 2048 + q0 + wave * 16 + lrow)) * 512 + h * 64;
#pragma unroll
  for (int dt = 0; dt < 4; ++dt) {
    bf16x4 ov;
#pragma unroll
    for (int r = 0; r < 4; ++r) ov[r] = (bf16)(o_acc[dt][r] * lr);
    *(bf16x4*)(Z + zrow + dt * 16 + quad * 4) = ov;  // packed 8B store
  }
}

// ---- layernorm: out = LN(a + s_f32) * g + b -------------------------------
template <bool A_BF16, bool OUT_BF16>
__global__ void __launch_bounds__(256) ln_k(const void* __restrict__ a_,
                                            const float* __restrict__ s,
                                            const float* __restrict__ g,
                                            const float* __restrict__ bta,
                                            void* __restrict__ out_) {
  int row = blockIdx.x * 4 + (threadIdx.x >> 6);
  int lane = threadIdx.x & 63;
  size_t base = (size_t)row * 512 + lane * 8;
  float x[8];
  float4 sa = *(const float4*)(s + base);
  float4 sb = *(const float4*)(s + base + 4);
  if constexpr (A_BF16) {
    bf16x8 av = *(const bf16x8*)((const bf16*)a_ + base);
    x[0] = (float)av[0] + sa.x; x[1] = (float)av[1] + sa.y;
    x[2] = (float)av[2] + sa.z; x[3] = (float)av[3] + sa.w;
    x[4] = (float)av[4] + sb.x; x[5] = (float)av[5] + sb.y;
    x[6] = (float)av[6] + sb.z; x[7] = (float)av[7] + sb.w;
  } else {
    float4 a0 = *(const float4*)((const float*)a_ + base);
    float4 a1 = *(const float4*)((const float*)a_ + base + 4);
    x[0] = a0.x + sa.x; x[1] = a0.y + sa.y; x[2] = a0.z + sa.z; x[3] = a0.w + sa.w;
    x[4] = a1.x + sb.x; x[5] = a1.y + sb.y; x[6] = a1.z + sb.z; x[7] = a1.w + sb.w;
  }
  float sum = 0.f;
#pragma unroll
  for (int i = 0; i < 8; ++i) sum += x[i];
#pragma unroll
  for (int off = 1; off < 64; off <<= 1) sum += __shfl_xor(sum, off, 64);
  float mu = sum * (1.0f / 512.0f);
  float vs = 0.f;
#pragma unroll
  for (int i = 0; i < 8; ++i) { float d = x[i] - mu; vs += d * d; }
#pragma unroll
  for (int off = 1; off < 64; off <<= 1) vs += __shfl_xor(vs, off, 64);
  float rstd = rsqrtf(vs * (1.0f / 512.0f) + 1e-5f);
  float4 g0 = *(const float4*)(g + lane * 8);
  float4 g1 = *(const float4*)(g + lane * 8 + 4);
  float4 b0 = *(const float4*)(bta + lane * 8);
  float4 b1 = *(const float4*)(bta + lane * 8 + 4);
  float gg[8] = {g0.x, g0.y, g0.z, g0.w, g1.x, g1.y, g1.z, g1.w};
  float bb[8] = {b0.x, b0.y, b0.z, b0.w, b1.x, b1.y, b1.z, b1.w};
  if constexpr (OUT_BF16) {
    bf16x8 o;
#pragma unroll
    for (int i = 0; i < 8; ++i)
      o[i] = (bf16)((x[i] - mu) * rstd * gg[i] + bb[i]);
    *(bf16x8*)((bf16*)out_ + base) = o;
  } else {
    float4 o0, o1;
    o0.x = (x[0] - mu) * rstd * gg[0] + bb[0];
    o0.y = (x[1] - mu) * rstd * gg[1] + bb[1];
    o0.z = (x[2] - mu) * rstd * gg[2] + bb[2];
    o0.w = (x[3] - mu) * rstd * gg[3] + bb[3];
    o1.x = (x[4] - mu) * rstd * gg[4] + bb[4];
    o1.y = (x[5] - mu) * rstd * gg[5] + bb[5];
    o1.z = (x[6] - mu) * rstd * gg[6] + bb[6];
    o1.w = (x[7] - mu) * rstd * gg[7] + bb[7];
    *(float4*)((float*)out_ + base) = o0;
    *(float4*)((float*)out_ + base + 4) = o1;
  }
}

extern "C" void kernel_launch(void* const* d_in, const int* in_sizes, int n_in,
                              void* d_out, int out_size, void* d_ws, size_t ws_size,
                              hipStream_t stream) {
  const float* qx = (const float*)d_in[0];
  const float* kx = (const float*)d_in[1];
  const float* vx = (const float*)d_in[2];
  const int* maskPAD = (const int*)d_in[3];
  const float* wq = (const float*)d_in[4];
  const float* bq = (const float*)d_in[5];
  const float* wk = (const float*)d_in[6];
  const float* bk = (const float*)d_in[7];
  const float* wv = (const float*)d_in[8];
  const float* bv = (const float*)d_in[9];
  const float* wo = (const float*)d_in[10];
  const float* bo = (const float*)d_in[11];
  const float* w1 = (const float*)d_in[12];
  const float* b1 = (const float*)d_in[13];
  const float* w2 = (const float*)d_in[14];
  const float* b2 = (const float*)d_in[15];
  const float* g1 = (const float*)d_in[16];
  const float* be1 = (const float*)d_in[17];
  const float* g2 = (const float*)d_in[18];
  const float* be2 = (const float*)d_in[19];

  char* w = (char*)d_ws;
  size_t off = 0;
  auto alloc = [&](size_t bytes) {
    void* p = w + off;
    off += (bytes + 255) & ~(size_t)255;
    return p;
  };
  bf16* wqT = (bf16*)alloc(512 * 512 * 2);
  bf16* wkT = (bf16*)alloc(512 * 512 * 2);
  bf16* wvT = (bf16*)alloc(512 * 512 * 2);
  bf16* woT = (bf16*)alloc(512 * 512 * 2);
  bf16* w1T = (bf16*)alloc(2048 * 512 * 2);
  bf16* w2T = (bf16*)alloc(512 * 2048 * 2);
  unsigned long long* mbits = (unsigned long long*)alloc((size_t)4 * 2048 * 32 * 8);
  size_t xall_bytes = (size_t)3 * 8192 * 512 * 2;           // 25.2 MB
  size_t act4 = (size_t)8192 * 512 * 2;                     // 8.4 MB
  // fast path needs xall + qh/kh/vt + z resident together
  bool fast = (off + xall_bytes + 4 * (act4 + 256)) <= ws_size;
  bf16* xall = fast ? (bf16*)alloc(xall_bytes) : nullptr;
  bf16* qh = (bf16*)alloc(act4);
  bf16* kh = (bf16*)alloc(act4);
  bf16* vt = (bf16*)alloc(act4);
  bf16* z = (bf16*)alloc(act4);
  float* s12;  // f32 [8192][512]
  bf16* zn;
  if (fast) {  // xall dead after qkv
    s12 = (float*)xall;
    zn = (bf16*)((char*)xall + (size_t)8192 * 512 * 4);
  } else {  // r6 scheme: over qh+kh / vt
    s12 = (float*)qh;
    zn = vt;
  }
  size_t h1_bytes = (size_t)8192 * 2048 * 2;
  bool big = (off + h1_bytes) <= ws_size;
  bf16* h1 = big ? (bf16*)alloc(h1_bytes) : z;

  dim3 tb(32, 8);
  transpose4_k<<<dim3(16, 16, 4), tb, 0, stream>>>(wq, wk, wv, wo, wqT, wkT, wvT, woT);
  transpose_k<<<dim3(64, 16), tb, 0, stream>>>(w1, w1T, 512, 2048);
  transpose_k<<<dim3(16, 64), tb, 0, stream>>>(w2, w2T, 2048, 512);
  maskbits_k<<<65536, 256, 0, stream>>>(maskPAD, mbits);
  if (fast) {
    cvt3_k<<<12288, 256, 0, stream>>>(qx, kx, vx, xall);
    qkv2_k<<<dim3(4, 192), 256, 0, stream>>>(xall, wqT, wkT, wvT, bq, bk, bv,
                                             qh, kh, vt);
  } else {
    qkv_k<<<dim3(4, 192), 256, 0, stream>>>(qx, kx, vx, wqT, wkT, wvT, bq, bk,
                                            bv, qh, kh, vt);
  }
  // flash attention -> z
  attn_k<<<dim3(32, 8, 4), 256, 0, stream>>>(qh, kh, vt, mbits, z);
  // out projection (TALL, 512 blocks) + LN1
  gemm_bt<4, true><<<dim3(8, 64), 256, 0, stream>>>(z, woT, bo, s12, 512, 512,
                                                    512, 512);
  ln_k<false, true><<<2048, 256, 0, stream>>>(vx, s12, g1, be1, zn);
  if (big) {
    gemm_bt<3, false><<<dim3(16, 64), 256, 0, stream>>>(zn, w1T, b1, h1, 2048,
                                                        512, 512, 512);
    gemm_bt<4, true><<<dim3(8, 64), 256, 0, stream>>>(h1, w2T, b2, s12, 512,
                                                      2048, 2048, 2048);
  } else {
    for (int p = 0; p < 4; ++p) {
      gemm_bt<3, true><<<dim3(8, 64), 256, 0, stream>>>(
          zn, w1T + (size_t)p * 512 * 512, b1 + p * 512, h1, 512, 512, 512, 512);
      if (p == 0)
        gemm_bt<4, true><<<dim3(8, 64), 256, 0, stream>>>(
            h1, w2T + p * 512, b2, s12, 512, 512, 512, 2048);
      else
        gemm_bt<5, true><<<dim3(8, 64), 256, 0, stream>>>(
            h1, w2T + p * 512, nullptr, s12, 512, 512, 512, 2048);
    }
  }
  ln_k<true, false><<<2048, 256, 0, stream>>>(zn, s12, g2, be2, (float*)d_out);
}